// Round 1
// baseline (1236.770 us; speedup 1.0000x reference)
//
#include <hip/hip_runtime.h>
#include <math.h>

#define NN 50000
#define NE 800000
#define DIM 128
#define NH 4
#define HD 32
#define EH (NE * NH)          // 3,200,000
#define ATTN_SCALE 0.17677669529663687f   // 1/sqrt(32)

// ---------------------------------------------------------------- QKV GEMM
// x[N,128] @ {Wq,Wk,Wv}[128,128] -> Q,K,V [N,128]. 8 rows per block.
__global__ __launch_bounds__(128) void qkv_kernel(
    const float* __restrict__ x,
    const float* __restrict__ Wq, const float* __restrict__ Wk,
    const float* __restrict__ Wv,
    float* __restrict__ Q, float* __restrict__ K, float* __restrict__ V)
{
    __shared__ float xs[DIM];
    const int j = threadIdx.x;
    const int row0 = blockIdx.x * 8;
    for (int r = 0; r < 8; ++r) {
        const int row = row0 + r;
        __syncthreads();
        xs[j] = x[row * DIM + j];
        __syncthreads();
        float aq = 0.f, ak = 0.f, av = 0.f;
        #pragma unroll 8
        for (int k = 0; k < DIM; ++k) {
            const float xv = xs[k];
            aq = fmaf(xv, Wq[k * DIM + j], aq);
            ak = fmaf(xv, Wk[k * DIM + j], ak);
            av = fmaf(xv, Wv[k * DIM + j], av);
        }
        Q[row * DIM + j] = aq;
        K[row * DIM + j] = ak;
        V[row * DIM + j] = av;
    }
}

// ------------------------------------------------------- edge attention
// one thread per (edge, head): 32-dim dot + edge bias + leaky relu.
// also produces per-block max for the global-max reduction.
__global__ __launch_bounds__(256) void attn_kernel(
    const float* __restrict__ Q, const float* __restrict__ K,
    const int* __restrict__ src, const int* __restrict__ dst,
    const float* __restrict__ edge_attr, const float* __restrict__ We,
    float* __restrict__ attn, float* __restrict__ blockmax)
{
    const int t = blockIdx.x * 256 + threadIdx.x;
    float val = -INFINITY;
    if (t < EH) {
        const int e = t >> 2;
        const int h = t & 3;
        const int s = src[e];
        const int d = dst[e];
        const float4* qp = (const float4*)(Q + (size_t)d * DIM + h * HD);
        const float4* kp = (const float4*)(K + (size_t)s * DIM + h * HD);
        float acc = 0.f;
        #pragma unroll
        for (int i = 0; i < 8; ++i) {
            const float4 q = qp[i];
            const float4 k = kp[i];
            acc += q.x * k.x + q.y * k.y + q.z * k.z + q.w * k.w;
        }
        const float eb = edge_attr[e * 3 + 0] * We[0 * NH + h]
                       + edge_attr[e * 3 + 1] * We[1 * NH + h]
                       + edge_attr[e * 3 + 2] * We[2 * NH + h];
        float a = acc * ATTN_SCALE + eb;
        a = (a >= 0.f) ? a : 0.2f * a;   // leaky_relu(0.2)
        attn[t] = a;
        val = a;
    }
    __shared__ float smax[256];
    smax[threadIdx.x] = val;
    __syncthreads();
    for (int s2 = 128; s2 > 0; s2 >>= 1) {
        if (threadIdx.x < s2)
            smax[threadIdx.x] = fmaxf(smax[threadIdx.x], smax[threadIdx.x + s2]);
        __syncthreads();
    }
    if (threadIdx.x == 0) blockmax[blockIdx.x] = smax[0];
}

// ------------------------------------------------------- global max (1 block)
__global__ __launch_bounds__(1024) void maxreduce_kernel(
    const float* __restrict__ blockmax, int n, float* __restrict__ gmax)
{
    __shared__ float smax[1024];
    float v = -INFINITY;
    for (int i = threadIdx.x; i < n; i += 1024) v = fmaxf(v, blockmax[i]);
    smax[threadIdx.x] = v;
    __syncthreads();
    for (int s = 512; s > 0; s >>= 1) {
        if (threadIdx.x < s)
            smax[threadIdx.x] = fmaxf(smax[threadIdx.x], smax[threadIdx.x + s]);
        __syncthreads();
    }
    if (threadIdx.x == 0) *gmax = smax[0];
}

// ------------------------------------------------------- exp + segment sum
__global__ __launch_bounds__(256) void expsum_kernel(
    float* __restrict__ attn, const int* __restrict__ dst,
    const float* __restrict__ gmax, float* __restrict__ attn_sum)
{
    const int t = blockIdx.x * 256 + threadIdx.x;
    if (t >= EH) return;
    const int e = t >> 2;
    const int h = t & 3;
    const float v = expf(attn[t] - *gmax);
    attn[t] = v;                       // attn buffer now holds attn_exp
    atomicAdd(&attn_sum[(size_t)dst[e] * NH + h], v);
}

// ------------------------------------------------------- weighted V scatter
// 128 threads per edge (2 edges per 256-block); atomicAdd into agg[dst].
__global__ __launch_bounds__(256) void agg_kernel(
    const float* __restrict__ attn_exp, const float* __restrict__ attn_sum,
    const int* __restrict__ src, const int* __restrict__ dst,
    const float* __restrict__ V, float* __restrict__ agg)
{
    const int t = blockIdx.x * 256 + threadIdx.x;
    const int e = t >> 7;
    if (e >= NE) return;
    const int c = t & 127;
    const int h = c >> 5;
    const int d = dst[e];
    const int s = src[e];
    const float ssum = attn_sum[(size_t)d * NH + h];
    const float coeff = attn_exp[(size_t)e * NH + h] / fmaxf(ssum, 1e-12f);
    atomicAdd(&agg[(size_t)d * DIM + c], V[(size_t)s * DIM + c] * coeff);
}

// ------------------------------------------------------- epilogue
// per node: agg@Wo+bo -> aggo; relu([x,aggo]@Wm+bm) -> out. 8 rows/block.
__global__ __launch_bounds__(128) void out_kernel(
    const float* __restrict__ x, const float* __restrict__ agg,
    const float* __restrict__ Wo, const float* __restrict__ bo,
    const float* __restrict__ Wm, const float* __restrict__ bm,
    float* __restrict__ out)
{
    __shared__ float xs[DIM], as[DIM], aggo[DIM];
    const int j = threadIdx.x;
    const int row0 = blockIdx.x * 8;
    for (int r = 0; r < 8; ++r) {
        const int row = row0 + r;
        __syncthreads();
        xs[j] = x[row * DIM + j];
        as[j] = agg[row * DIM + j];
        __syncthreads();
        float acc = bo[j];
        #pragma unroll 8
        for (int k = 0; k < DIM; ++k)
            acc = fmaf(as[k], Wo[k * DIM + j], acc);
        aggo[j] = acc;
        __syncthreads();
        float acc2 = bm[j];
        #pragma unroll 8
        for (int k = 0; k < DIM; ++k)
            acc2 = fmaf(xs[k], Wm[k * DIM + j], acc2);
        #pragma unroll 8
        for (int k = 0; k < DIM; ++k)
            acc2 = fmaf(aggo[k], Wm[(DIM + k) * DIM + j], acc2);
        out[row * DIM + j] = fmaxf(acc2, 0.f);
    }
}

// ----------------------------------------------------------------- launch
extern "C" void kernel_launch(void* const* d_in, const int* in_sizes, int n_in,
                              void* d_out, int out_size, void* d_ws, size_t ws_size,
                              hipStream_t stream)
{
    const float* x         = (const float*)d_in[0];
    const int*   edge_idx  = (const int*)d_in[1];   // [2,E]: row0=src, row1=dst
    const float* edge_attr = (const float*)d_in[2];
    const float* Wq        = (const float*)d_in[3];
    const float* Wk        = (const float*)d_in[4];
    const float* Wv        = (const float*)d_in[5];
    const float* We        = (const float*)d_in[6];
    const float* Wo        = (const float*)d_in[7];
    const float* bo        = (const float*)d_in[8];
    const float* Wm        = (const float*)d_in[9];
    const float* bm        = (const float*)d_in[10];
    float* out = (float*)d_out;

    const int* src = edge_idx;
    const int* dst = edge_idx + NE;

    // workspace layout (floats)
    float* ws = (float*)d_ws;
    float* Q        = ws;                       // 6.4M
    float* K        = Q + (size_t)NN * DIM;     // 6.4M
    float* V        = K + (size_t)NN * DIM;     // 6.4M
    float* attn     = V + (size_t)NN * DIM;     // 3.2M  (attn, then attn_exp)
    float* attn_sum = attn + (size_t)EH;        // 200K
    float* agg      = attn_sum + (size_t)NN * NH; // 6.4M
    float* blockmax = agg + (size_t)NN * DIM;   // 12.5K
    float* gmax     = blockmax + 13000;         // 1

    // zero the accumulators (harness poisons ws with 0xAA before every launch)
    hipMemsetAsync(attn_sum, 0, (size_t)NN * NH * sizeof(float), stream);
    hipMemsetAsync(agg, 0, (size_t)NN * DIM * sizeof(float), stream);

    const int attn_blocks = (EH + 255) / 256;   // 12500

    qkv_kernel<<<NN / 8, 128, 0, stream>>>(x, Wq, Wk, Wv, Q, K, V);
    attn_kernel<<<attn_blocks, 256, 0, stream>>>(Q, K, src, dst, edge_attr, We,
                                                 attn, blockmax);
    maxreduce_kernel<<<1, 1024, 0, stream>>>(blockmax, attn_blocks, gmax);
    expsum_kernel<<<attn_blocks, 256, 0, stream>>>(attn, dst, gmax, attn_sum);
    agg_kernel<<<(NE * 128) / 256, 256, 0, stream>>>(attn, attn_sum, src, dst,
                                                     V, agg);
    out_kernel<<<NN / 8, 128, 0, stream>>>(x, agg, Wo, bo, Wm, bm, out);
}

// Round 3
// 885.760 us; speedup vs baseline: 1.3963x; 1.3963x over previous
//
#include <hip/hip_runtime.h>
#include <math.h>

#define NN 50000
#define NE 800000
#define DIM 128
#define NH 4
#define HD 32
#define EH (NE * NH)          // 3,200,000
#define ATTN_SCALE 0.17677669529663687f   // 1/sqrt(32)
#define RT 16                 // rows per block-tile in dense GEMMs (50000 = 16*3125)
#define NB 49                 // scan blocks: ceil(50000/1024)

// ---------------------------------------------------------------- QKV GEMM
// x[N,128] @ {Wq,Wk,Wv}[128,128] -> Q,K,V.  Register-blocked over RT rows so
// weights are read once per RT rows (L2 weight traffic /16).
__global__ __launch_bounds__(128) void qkv_kernel(
    const float* __restrict__ x,
    const float* __restrict__ Wq, const float* __restrict__ Wk,
    const float* __restrict__ Wv,
    float* __restrict__ Q, float* __restrict__ K, float* __restrict__ V)
{
    __shared__ float xs[RT][DIM];
    const int j = threadIdx.x;
    const int row0 = blockIdx.x * RT;
    #pragma unroll
    for (int r = 0; r < RT; ++r) xs[r][j] = x[(size_t)(row0 + r) * DIM + j];
    __syncthreads();

    float aq[RT], ak[RT], av[RT];
    #pragma unroll
    for (int r = 0; r < RT; ++r) { aq[r] = 0.f; ak[r] = 0.f; av[r] = 0.f; }

    for (int k = 0; k < DIM; ++k) {
        const float wq = Wq[k * DIM + j];
        const float wk = Wk[k * DIM + j];
        const float wv = Wv[k * DIM + j];
        #pragma unroll
        for (int r = 0; r < RT; ++r) {
            const float xv = xs[r][k];
            aq[r] = fmaf(xv, wq, aq[r]);
            ak[r] = fmaf(xv, wk, ak[r]);
            av[r] = fmaf(xv, wv, av[r]);
        }
    }
    #pragma unroll
    for (int r = 0; r < RT; ++r) {
        Q[(size_t)(row0 + r) * DIM + j] = aq[r];
        K[(size_t)(row0 + r) * DIM + j] = ak[r];
        V[(size_t)(row0 + r) * DIM + j] = av[r];
    }
}

// ---------------------------------------------------------------- CSR build
__global__ __launch_bounds__(256) void zero_deg_kernel(int* __restrict__ deg)
{
    const int i = blockIdx.x * 256 + threadIdx.x;
    if (i < NN) deg[i] = 0;
}

__global__ __launch_bounds__(256) void hist_kernel(
    const int* __restrict__ dst, int* __restrict__ deg)
{
    const int e = blockIdx.x * 256 + threadIdx.x;
    if (e < NE) atomicAdd(&deg[dst[e]], 1);
}

// per-block exclusive scan of 1024 ints (Hillis-Steele, double-sync)
__global__ __launch_bounds__(1024) void scanA_kernel(
    const int* __restrict__ deg, int* __restrict__ rowptr,
    int* __restrict__ blocksum)
{
    __shared__ int s[1024];
    const int tid = threadIdx.x;
    const int i = blockIdx.x * 1024 + tid;
    const int v = (i < NN) ? deg[i] : 0;
    s[tid] = v;
    __syncthreads();
    for (int off = 1; off < 1024; off <<= 1) {
        const int add = (tid >= off) ? s[tid - off] : 0;
        __syncthreads();
        s[tid] += add;
        __syncthreads();
    }
    if (i < NN) rowptr[i] = s[tid] - v;        // exclusive, pre-offset
    if (tid == 1023) blocksum[blockIdx.x] = s[1023];
}

__global__ void scanB_kernel(const int* __restrict__ blocksum,
                             int* __restrict__ blockoff,
                             int* __restrict__ rowptr)
{
    if (blockIdx.x == 0 && threadIdx.x == 0) {
        int run = 0;
        for (int b = 0; b < NB; ++b) { blockoff[b] = run; run += blocksum[b]; }
        rowptr[NN] = run;    // == NE
    }
}

__global__ __launch_bounds__(256) void scanC_kernel(
    int* __restrict__ rowptr, int* __restrict__ cursor,
    const int* __restrict__ blockoff)
{
    const int i = blockIdx.x * 256 + threadIdx.x;
    if (i < NN) {
        const int r = rowptr[i] + blockoff[i >> 10];
        rowptr[i] = r;
        cursor[i] = r;
    }
}

__global__ __launch_bounds__(256) void scatter_kernel(
    const int* __restrict__ dst, int* __restrict__ cursor,
    int* __restrict__ eid)
{
    const int e = blockIdx.x * 256 + threadIdx.x;
    if (e < NE) {
        const int pos = atomicAdd(&cursor[dst[e]], 1);
        eid[pos] = e;
    }
}

// ------------------------------------------------------- edge attention
// writes PRE-exp attn (leaky-relu applied) + per-block max.
__global__ __launch_bounds__(256) void attn_kernel(
    const float* __restrict__ Q, const float* __restrict__ K,
    const int* __restrict__ src, const int* __restrict__ dst,
    const float* __restrict__ edge_attr, const float* __restrict__ We,
    float* __restrict__ attn, float* __restrict__ blockmax)
{
    const int t = blockIdx.x * 256 + threadIdx.x;
    float val = -INFINITY;
    if (t < EH) {
        const int e = t >> 2;
        const int h = t & 3;
        const int s = src[e];
        const int d = dst[e];
        const float4* qp = (const float4*)(Q + (size_t)d * DIM + h * HD);
        const float4* kp = (const float4*)(K + (size_t)s * DIM + h * HD);
        float acc = 0.f;
        #pragma unroll
        for (int i = 0; i < 8; ++i) {
            const float4 q = qp[i];
            const float4 k = kp[i];
            acc += q.x * k.x + q.y * k.y + q.z * k.z + q.w * k.w;
        }
        const float eb = edge_attr[e * 3 + 0] * We[0 * NH + h]
                       + edge_attr[e * 3 + 1] * We[1 * NH + h]
                       + edge_attr[e * 3 + 2] * We[2 * NH + h];
        float a = acc * ATTN_SCALE + eb;
        a = (a >= 0.f) ? a : 0.2f * a;   // leaky_relu(0.2)
        attn[t] = a;
        val = a;
    }
    __shared__ float smax[256];
    smax[threadIdx.x] = val;
    __syncthreads();
    for (int s2 = 128; s2 > 0; s2 >>= 1) {
        if (threadIdx.x < s2)
            smax[threadIdx.x] = fmaxf(smax[threadIdx.x], smax[threadIdx.x + s2]);
        __syncthreads();
    }
    if (threadIdx.x == 0) blockmax[blockIdx.x] = smax[0];
}

__global__ __launch_bounds__(1024) void maxreduce_kernel(
    const float* __restrict__ blockmax, int n, float* __restrict__ gmax)
{
    __shared__ float smax[1024];
    float v = -INFINITY;
    for (int i = threadIdx.x; i < n; i += 1024) v = fmaxf(v, blockmax[i]);
    smax[threadIdx.x] = v;
    __syncthreads();
    for (int s = 512; s > 0; s >>= 1) {
        if (threadIdx.x < s)
            smax[threadIdx.x] = fmaxf(smax[threadIdx.x], smax[threadIdx.x + s]);
        __syncthreads();
    }
    if (threadIdx.x == 0) *gmax = smax[0];
}

// ------------------------------------------------------- CSR softmax+gather
// 2 nodes per 256-block (128 threads = columns per node). Zero atomics:
// pass 1 computes the per-(node,head) exp-sum; pass 2 accumulates weighted V
// in registers and writes agg (into d_out, reused as scratch) exactly once.
__global__ __launch_bounds__(256) void agg_gather_kernel(
    const float* __restrict__ attn, const float* __restrict__ gmax,
    const int* __restrict__ rowptr, const int* __restrict__ eid,
    const int* __restrict__ src, const float* __restrict__ V,
    float* __restrict__ aggout)
{
    const int tid = threadIdx.x;
    const int d = blockIdx.x * 2 + (tid >> 7);
    const int j = tid & 127;
    const int h = j >> 5;
    const float m = *gmax;
    const int begin = rowptr[d];
    const int end   = rowptr[d + 1];

    float ssum = 0.f;
    for (int p = begin; p < end; ++p)
        ssum += expf(attn[eid[p] * NH + h] - m);
    const float inv = 1.f / fmaxf(ssum, 1e-12f);

    float acc = 0.f;
    for (int p = begin; p < end; ++p) {
        const int e = eid[p];
        const float w = expf(attn[e * NH + h] - m) * inv;
        acc = fmaf(V[(size_t)src[e] * DIM + j], w, acc);
    }
    aggout[(size_t)d * DIM + j] = acc;
}

// ------------------------------------------------------- epilogue
// io == d_out: rows hold agg on entry, final output on exit. Each block
// stages its own RT rows in LDS then overwrites them (block-disjoint).
__global__ __launch_bounds__(128) void out_kernel(
    const float* __restrict__ x,
    const float* __restrict__ Wo, const float* __restrict__ bo,
    const float* __restrict__ Wm, const float* __restrict__ bm,
    float* __restrict__ io)
{
    __shared__ float xs[RT][DIM];
    __shared__ float as[RT][DIM];
    __shared__ float aggo[RT][DIM];
    const int j = threadIdx.x;
    const int row0 = blockIdx.x * RT;
    #pragma unroll
    for (int r = 0; r < RT; ++r) {
        xs[r][j] = x[(size_t)(row0 + r) * DIM + j];
        as[r][j] = io[(size_t)(row0 + r) * DIM + j];
    }
    __syncthreads();

    float acc[RT];
    {
        const float b = bo[j];
        #pragma unroll
        for (int r = 0; r < RT; ++r) acc[r] = b;
    }
    for (int k = 0; k < DIM; ++k) {
        const float wo = Wo[k * DIM + j];
        #pragma unroll
        for (int r = 0; r < RT; ++r) acc[r] = fmaf(as[r][k], wo, acc[r]);
    }
    #pragma unroll
    for (int r = 0; r < RT; ++r) aggo[r][j] = acc[r];
    __syncthreads();

    float acc2[RT];
    {
        const float b = bm[j];
        #pragma unroll
        for (int r = 0; r < RT; ++r) acc2[r] = b;
    }
    for (int k = 0; k < DIM; ++k) {
        const float wm = Wm[k * DIM + j];
        #pragma unroll
        for (int r = 0; r < RT; ++r) acc2[r] = fmaf(xs[r][k], wm, acc2[r]);
    }
    for (int k = 0; k < DIM; ++k) {
        const float wm = Wm[(DIM + k) * DIM + j];
        #pragma unroll
        for (int r = 0; r < RT; ++r) acc2[r] = fmaf(aggo[r][k], wm, acc2[r]);
    }
    #pragma unroll
    for (int r = 0; r < RT; ++r)
        io[(size_t)(row0 + r) * DIM + j] = fmaxf(acc2[r], 0.f);
}

// ----------------------------------------------------------------- launch
extern "C" void kernel_launch(void* const* d_in, const int* in_sizes, int n_in,
                              void* d_out, int out_size, void* d_ws, size_t ws_size,
                              hipStream_t stream)
{
    const float* x         = (const float*)d_in[0];
    const int*   edge_idx  = (const int*)d_in[1];   // [2,E]: row0=src, row1=dst
    const float* edge_attr = (const float*)d_in[2];
    const float* Wq        = (const float*)d_in[3];
    const float* Wk        = (const float*)d_in[4];
    const float* Wv        = (const float*)d_in[5];
    const float* We        = (const float*)d_in[6];
    const float* Wo        = (const float*)d_in[7];
    const float* bo        = (const float*)d_in[8];
    const float* Wm        = (const float*)d_in[9];
    const float* bm        = (const float*)d_in[10];
    float* out = (float*)d_out;

    const int* src = edge_idx;
    const int* dst = edge_idx + NE;

    // workspace layout (word offsets; all 16B-aligned). Total ~93.4 MB.
    float* ws = (float*)d_ws;
    float* Q        = ws;                         //  6,400,000 f
    float* K        = Q + (size_t)NN * DIM;       //  6,400,000 f
    float* V        = K + (size_t)NN * DIM;       //  6,400,000 f
    float* attn     = V + (size_t)NN * DIM;       //  3,200,000 f (pre-exp)
    float* blockmax = attn + (size_t)EH;          //  12,544 f (12500 used)
    float* gmax     = blockmax + 12544;           //  64 f (1 used)
    int*   deg      = (int*)(gmax + 64);          //  50,048 i (50000 used)
    int*   rowptr   = deg + 50048;                //  50,048 i (50001 used)
    int*   cursor   = rowptr + 50048;             //  50,048 i (50000 used)
    int*   eid      = cursor + 50048;             //  800,000 i
    int*   blocksum = eid + 800000;               //  64 i (NB used)
    int*   blockoff = blocksum + 64;              //  64 i (NB used)

    const int attn_blocks = (EH + 255) / 256;     // 12500 (exact: EH = 12500*256)

    // CSR build (int atomics only; no memset nodes in the graph)
    zero_deg_kernel<<<(NN + 255) / 256, 256, 0, stream>>>(deg);
    hist_kernel<<<(NE + 255) / 256, 256, 0, stream>>>(dst, deg);
    scanA_kernel<<<NB, 1024, 0, stream>>>(deg, rowptr, blocksum);
    scanB_kernel<<<1, 64, 0, stream>>>(blocksum, blockoff, rowptr);
    scanC_kernel<<<(NN + 255) / 256, 256, 0, stream>>>(rowptr, cursor, blockoff);
    scatter_kernel<<<(NE + 255) / 256, 256, 0, stream>>>(dst, cursor, eid);

    // main pipeline
    qkv_kernel<<<NN / RT, 128, 0, stream>>>(x, Wq, Wk, Wv, Q, K, V);
    attn_kernel<<<attn_blocks, 256, 0, stream>>>(Q, K, src, dst, edge_attr, We,
                                                 attn, blockmax);
    maxreduce_kernel<<<1, 1024, 0, stream>>>(blockmax, attn_blocks, gmax);
    agg_gather_kernel<<<NN / 2, 256, 0, stream>>>(attn, gmax, rowptr, eid,
                                                  src, V, out);
    out_kernel<<<NN / RT, 128, 0, stream>>>(x, Wo, bo, Wm, bm, out);
}

// Round 4
// 639.516 us; speedup vs baseline: 1.9339x; 1.3850x over previous
//
#include <hip/hip_runtime.h>
#include <hip/hip_bf16.h>
#include <math.h>

#define NN 50000
#define NE 800000
#define DIM 128
#define NH 4
#define HD 32
#define EH (NE * NH)          // 3,200,000
#define ATTN_SCALE 0.17677669529663687f   // 1/sqrt(32)
#define RT 16                 // rows per block-tile in dense GEMMs (50000 = 16*3125)
#define NB 49                 // scan blocks: ceil(50000/1024)

typedef unsigned int uint;
typedef unsigned short ushort;

__device__ inline ushort f2bf(float f) {
    __hip_bfloat16 h = __float2bfloat16(f);   // round-to-nearest
    return *(ushort*)&h;
}
// dot of a packed bf16 pair (uint) against another pair, fp32 math
__device__ inline float pairdot(uint q, uint k) {
    const float qlo = __uint_as_float(q << 16);
    const float qhi = __uint_as_float(q & 0xffff0000u);
    const float klo = __uint_as_float(k << 16);
    const float khi = __uint_as_float(k & 0xffff0000u);
    return fmaf(qlo, klo, qhi * khi);
}

// ---------------------------------------------------------------- QKV GEMM
// x[N,128] @ {Wq,Wk,Wv}[128,128] -> Q,K,V stored as bf16 (fp32 accumulate).
__global__ __launch_bounds__(128) void qkv_kernel(
    const float* __restrict__ x,
    const float* __restrict__ Wq, const float* __restrict__ Wk,
    const float* __restrict__ Wv,
    ushort* __restrict__ Qb, ushort* __restrict__ Kb, ushort* __restrict__ Vb)
{
    __shared__ float xs[RT][DIM];
    const int j = threadIdx.x;
    const int row0 = blockIdx.x * RT;
    #pragma unroll
    for (int r = 0; r < RT; ++r) xs[r][j] = x[(size_t)(row0 + r) * DIM + j];
    __syncthreads();

    float aq[RT], ak[RT], av[RT];
    #pragma unroll
    for (int r = 0; r < RT; ++r) { aq[r] = 0.f; ak[r] = 0.f; av[r] = 0.f; }

    for (int k = 0; k < DIM; ++k) {
        const float wq = Wq[k * DIM + j];
        const float wk = Wk[k * DIM + j];
        const float wv = Wv[k * DIM + j];
        #pragma unroll
        for (int r = 0; r < RT; ++r) {
            const float xv = xs[r][k];
            aq[r] = fmaf(xv, wq, aq[r]);
            ak[r] = fmaf(xv, wk, ak[r]);
            av[r] = fmaf(xv, wv, av[r]);
        }
    }
    #pragma unroll
    for (int r = 0; r < RT; ++r) {
        Qb[(size_t)(row0 + r) * DIM + j] = f2bf(aq[r]);
        Kb[(size_t)(row0 + r) * DIM + j] = f2bf(ak[r]);
        Vb[(size_t)(row0 + r) * DIM + j] = f2bf(av[r]);
    }
}

// ---------------------------------------------------------------- CSR build
__global__ __launch_bounds__(256) void zero_deg_kernel(int* __restrict__ deg)
{
    const int i = blockIdx.x * 256 + threadIdx.x;
    if (i < NN) deg[i] = 0;
}

__global__ __launch_bounds__(256) void hist_kernel(
    const int* __restrict__ dst, int* __restrict__ deg)
{
    const int e = blockIdx.x * 256 + threadIdx.x;
    if (e < NE) atomicAdd(&deg[dst[e]], 1);
}

__global__ __launch_bounds__(1024) void scanA_kernel(
    const int* __restrict__ deg, int* __restrict__ rowptr,
    int* __restrict__ blocksum)
{
    __shared__ int s[1024];
    const int tid = threadIdx.x;
    const int i = blockIdx.x * 1024 + tid;
    const int v = (i < NN) ? deg[i] : 0;
    s[tid] = v;
    __syncthreads();
    for (int off = 1; off < 1024; off <<= 1) {
        const int add = (tid >= off) ? s[tid - off] : 0;
        __syncthreads();
        s[tid] += add;
        __syncthreads();
    }
    if (i < NN) rowptr[i] = s[tid] - v;        // exclusive, pre-offset
    if (tid == 1023) blocksum[blockIdx.x] = s[1023];
}

__global__ void scanB_kernel(const int* __restrict__ blocksum,
                             int* __restrict__ blockoff,
                             int* __restrict__ rowptr)
{
    if (blockIdx.x == 0 && threadIdx.x == 0) {
        int run = 0;
        for (int b = 0; b < NB; ++b) { blockoff[b] = run; run += blocksum[b]; }
        rowptr[NN] = run;    // == NE
    }
}

__global__ __launch_bounds__(256) void scanC_kernel(
    int* __restrict__ rowptr, int* __restrict__ cursor,
    const int* __restrict__ blockoff)
{
    const int i = blockIdx.x * 256 + threadIdx.x;
    if (i < NN) {
        const int r = rowptr[i] + blockoff[i >> 10];
        rowptr[i] = r;
        cursor[i] = r;
    }
}

__global__ __launch_bounds__(256) void scatter_kernel(
    const int* __restrict__ dst, int* __restrict__ cursor,
    int* __restrict__ eid)
{
    const int e = blockIdx.x * 256 + threadIdx.x;
    if (e < NE) {
        const int pos = atomicAdd(&cursor[dst[e]], 1);
        eid[pos] = e;
    }
}

// ------------------------------------------------------- edge attention
// bf16 Q/K gather (512 B/edge instead of 1 KB); fp32 math.
__global__ __launch_bounds__(256) void attn_kernel(
    const ushort* __restrict__ Qb, const ushort* __restrict__ Kb,
    const int* __restrict__ src, const int* __restrict__ dst,
    const float* __restrict__ edge_attr, const float* __restrict__ We,
    float* __restrict__ attn, float* __restrict__ blockmax)
{
    const int t = blockIdx.x * 256 + threadIdx.x;
    float val = -INFINITY;
    if (t < EH) {
        const int e = t >> 2;
        const int h = t & 3;
        const int s = src[e];
        const int d = dst[e];
        const uint4* qv = (const uint4*)(Qb + (size_t)d * DIM + h * HD);
        const uint4* kv = (const uint4*)(Kb + (size_t)s * DIM + h * HD);
        float acc = 0.f;
        #pragma unroll
        for (int i = 0; i < 4; ++i) {
            const uint4 q = qv[i];
            const uint4 k = kv[i];
            acc += pairdot(q.x, k.x) + pairdot(q.y, k.y)
                 + pairdot(q.z, k.z) + pairdot(q.w, k.w);
        }
        const float eb = edge_attr[e * 3 + 0] * We[0 * NH + h]
                       + edge_attr[e * 3 + 1] * We[1 * NH + h]
                       + edge_attr[e * 3 + 2] * We[2 * NH + h];
        float a = acc * ATTN_SCALE + eb;
        a = (a >= 0.f) ? a : 0.2f * a;   // leaky_relu(0.2)
        attn[t] = a;
        val = a;
    }
    __shared__ float smax[256];
    smax[threadIdx.x] = val;
    __syncthreads();
    for (int s2 = 128; s2 > 0; s2 >>= 1) {
        if (threadIdx.x < s2)
            smax[threadIdx.x] = fmaxf(smax[threadIdx.x], smax[threadIdx.x + s2]);
        __syncthreads();
    }
    if (threadIdx.x == 0) blockmax[blockIdx.x] = smax[0];
}

__global__ __launch_bounds__(1024) void maxreduce_kernel(
    const float* __restrict__ blockmax, int n, float* __restrict__ gmax)
{
    __shared__ float smax[1024];
    float v = -INFINITY;
    for (int i = threadIdx.x; i < n; i += 1024) v = fmaxf(v, blockmax[i]);
    smax[threadIdx.x] = v;
    __syncthreads();
    for (int s = 512; s > 0; s >>= 1) {
        if (threadIdx.x < s)
            smax[threadIdx.x] = fmaxf(smax[threadIdx.x], smax[threadIdx.x + s]);
        __syncthreads();
    }
    if (threadIdx.x == 0) *gmax = smax[0];
}

// ------------------------------------------------------- CSR softmax+gather
// ONE WAVE PER NODE (64 lanes, 2 columns each via packed-bf16 uint loads):
// wave-uniform loop bounds, one coalesced 256 B transaction per edge.
__global__ __launch_bounds__(256) void agg_gather_kernel(
    const float* __restrict__ attn, const float* __restrict__ gmax,
    const int* __restrict__ rowptr, const int* __restrict__ eid,
    const int* __restrict__ src, const ushort* __restrict__ Vb,
    float* __restrict__ aggout)
{
    const int tid = threadIdx.x;
    const int d = blockIdx.x * 4 + (tid >> 6);
    const int jj = tid & 63;          // column-pair index: cols 2jj, 2jj+1
    const int h = jj >> 4;            // head of both columns
    const float m = *gmax;
    const int begin = rowptr[d];
    const int end   = rowptr[d + 1];

    float ssum = 0.f;
    for (int p = begin; p < end; ++p)
        ssum += expf(attn[eid[p] * NH + h] - m);
    const float inv = 1.f / fmaxf(ssum, 1e-12f);

    float a0 = 0.f, a1 = 0.f;
    for (int p = begin; p < end; ++p) {
        const int e = eid[p];
        const float w = expf(attn[e * NH + h] - m) * inv;
        const uint u = *(const uint*)(Vb + (size_t)src[e] * DIM + 2 * jj);
        a0 = fmaf(__uint_as_float(u << 16), w, a0);
        a1 = fmaf(__uint_as_float(u & 0xffff0000u), w, a1);
    }
    float2* outp = (float2*)(aggout + (size_t)d * DIM + 2 * jj);
    *outp = make_float2(a0, a1);
}

// ------------------------------------------------------- epilogue
// io == d_out: rows hold agg on entry, final output on exit (block-disjoint).
__global__ __launch_bounds__(128) void out_kernel(
    const float* __restrict__ x,
    const float* __restrict__ Wo, const float* __restrict__ bo,
    const float* __restrict__ Wm, const float* __restrict__ bm,
    float* __restrict__ io)
{
    __shared__ float xs[RT][DIM];
    __shared__ float as[RT][DIM];
    __shared__ float aggo[RT][DIM];
    const int j = threadIdx.x;
    const int row0 = blockIdx.x * RT;
    #pragma unroll
    for (int r = 0; r < RT; ++r) {
        xs[r][j] = x[(size_t)(row0 + r) * DIM + j];
        as[r][j] = io[(size_t)(row0 + r) * DIM + j];
    }
    __syncthreads();

    float acc[RT];
    {
        const float b = bo[j];
        #pragma unroll
        for (int r = 0; r < RT; ++r) acc[r] = b;
    }
    for (int k = 0; k < DIM; ++k) {
        const float wo = Wo[k * DIM + j];
        #pragma unroll
        for (int r = 0; r < RT; ++r) acc[r] = fmaf(as[r][k], wo, acc[r]);
    }
    #pragma unroll
    for (int r = 0; r < RT; ++r) aggo[r][j] = acc[r];
    __syncthreads();

    float acc2[RT];
    {
        const float b = bm[j];
        #pragma unroll
        for (int r = 0; r < RT; ++r) acc2[r] = b;
    }
    for (int k = 0; k < DIM; ++k) {
        const float wm = Wm[k * DIM + j];
        #pragma unroll
        for (int r = 0; r < RT; ++r) acc2[r] = fmaf(xs[r][k], wm, acc2[r]);
    }
    for (int k = 0; k < DIM; ++k) {
        const float wm = Wm[(DIM + k) * DIM + j];
        #pragma unroll
        for (int r = 0; r < RT; ++r) acc2[r] = fmaf(aggo[r][k], wm, acc2[r]);
    }
    #pragma unroll
    for (int r = 0; r < RT; ++r)
        io[(size_t)(row0 + r) * DIM + j] = fmaxf(acc2[r], 0.f);
}

// ----------------------------------------------------------------- launch
extern "C" void kernel_launch(void* const* d_in, const int* in_sizes, int n_in,
                              void* d_out, int out_size, void* d_ws, size_t ws_size,
                              hipStream_t stream)
{
    const float* x         = (const float*)d_in[0];
    const int*   edge_idx  = (const int*)d_in[1];   // [2,E]: row0=src, row1=dst
    const float* edge_attr = (const float*)d_in[2];
    const float* Wq        = (const float*)d_in[3];
    const float* Wk        = (const float*)d_in[4];
    const float* Wv        = (const float*)d_in[5];
    const float* We        = (const float*)d_in[6];
    const float* Wo        = (const float*)d_in[7];
    const float* bo        = (const float*)d_in[8];
    const float* Wm        = (const float*)d_in[9];
    const float* bm        = (const float*)d_in[10];
    float* out = (float*)d_out;

    const int* src = edge_idx;
    const int* dst = edge_idx + NE;

    // workspace layout. Qb/Kb/Vb bf16 (12.8 MB each), attn fp32 (12.8 MB).
    ushort* Qb = (ushort*)d_ws;                   // 6,400,000 us
    ushort* Kb = Qb + (size_t)NN * DIM;           // 6,400,000 us
    ushort* Vb = Kb + (size_t)NN * DIM;           // 6,400,000 us
    float* attn     = (float*)(Vb + (size_t)NN * DIM);  // 3,200,000 f
    float* blockmax = attn + (size_t)EH;          // 12,544 f (12500 used)
    float* gmax     = blockmax + 12544;           // 64 f (1 used)
    int*   deg      = (int*)(gmax + 64);          // 50,048 i
    int*   rowptr   = deg + 50048;                // 50,048 i (50001 used)
    int*   cursor   = rowptr + 50048;             // 50,048 i
    int*   eid      = cursor + 50048;             // 800,000 i
    int*   blocksum = eid + 800000;               // 64 i (NB used)
    int*   blockoff = blocksum + 64;              // 64 i (NB used)

    const int attn_blocks = (EH + 255) / 256;     // 12500 (exact)

    // CSR build (int atomics only)
    zero_deg_kernel<<<(NN + 255) / 256, 256, 0, stream>>>(deg);
    hist_kernel<<<(NE + 255) / 256, 256, 0, stream>>>(dst, deg);
    scanA_kernel<<<NB, 1024, 0, stream>>>(deg, rowptr, blocksum);
    scanB_kernel<<<1, 64, 0, stream>>>(blocksum, blockoff, rowptr);
    scanC_kernel<<<(NN + 255) / 256, 256, 0, stream>>>(rowptr, cursor, blockoff);
    scatter_kernel<<<(NE + 255) / 256, 256, 0, stream>>>(dst, cursor, eid);

    // main pipeline
    qkv_kernel<<<NN / RT, 128, 0, stream>>>(x, Wq, Wk, Wv, Qb, Kb, Vb);
    attn_kernel<<<attn_blocks, 256, 0, stream>>>(Qb, Kb, src, dst, edge_attr, We,
                                                 attn, blockmax);
    maxreduce_kernel<<<1, 1024, 0, stream>>>(blockmax, attn_blocks, gmax);
    agg_gather_kernel<<<NN / 4, 256, 0, stream>>>(attn, gmax, rowptr, eid,
                                                  src, Vb, out);
    out_kernel<<<NN / RT, 128, 0, stream>>>(x, Wo, bo, Wm, bm, out);
}

// Round 5
// 476.294 us; speedup vs baseline: 2.5967x; 1.3427x over previous
//
#include <hip/hip_runtime.h>
#include <hip/hip_bf16.h>
#include <math.h>

#define NN 50000
#define NE 800000
#define DIM 128
#define NH 4
#define HD 32
#define EH (NE * NH)          // 3,200,000
#define ATTN_SCALE 0.17677669529663687f   // 1/sqrt(32)
#define RT 16                 // rows per block-tile in dense GEMMs (50000 = 16*3125)
#define NB 49                 // scan blocks: ceil(50000/1024)

typedef unsigned int uint;
typedef unsigned short ushort;

__device__ inline ushort f2bf(float f) {
    __hip_bfloat16 h = __float2bfloat16(f);   // round-to-nearest
    return *(ushort*)&h;
}
__device__ inline float bflo(uint u) { return __uint_as_float(u << 16); }
__device__ inline float bfhi(uint u) { return __uint_as_float(u & 0xffff0000u); }
// dot of a packed bf16 pair (uint) against another pair, fp32 math
__device__ inline float pairdot(uint q, uint k) {
    return fmaf(bflo(q), bflo(k), bfhi(q) * bfhi(k));
}

// ---------------------------------------------------------------- QKV GEMM
// x[N,128] @ {Wq,Wk,Wv}[128,128] -> Q,K,V stored as bf16 (fp32 accumulate).
__global__ __launch_bounds__(128) void qkv_kernel(
    const float* __restrict__ x,
    const float* __restrict__ Wq, const float* __restrict__ Wk,
    const float* __restrict__ Wv,
    ushort* __restrict__ Qb, ushort* __restrict__ Kb, ushort* __restrict__ Vb)
{
    __shared__ float xs[RT][DIM];
    const int j = threadIdx.x;
    const int row0 = blockIdx.x * RT;
    #pragma unroll
    for (int r = 0; r < RT; ++r) xs[r][j] = x[(size_t)(row0 + r) * DIM + j];
    __syncthreads();

    float aq[RT], ak[RT], av[RT];
    #pragma unroll
    for (int r = 0; r < RT; ++r) { aq[r] = 0.f; ak[r] = 0.f; av[r] = 0.f; }

    for (int k = 0; k < DIM; ++k) {
        const float wq = Wq[k * DIM + j];
        const float wk = Wk[k * DIM + j];
        const float wv = Wv[k * DIM + j];
        #pragma unroll
        for (int r = 0; r < RT; ++r) {
            const float xv = xs[r][k];
            aq[r] = fmaf(xv, wq, aq[r]);
            ak[r] = fmaf(xv, wk, ak[r]);
            av[r] = fmaf(xv, wv, av[r]);
        }
    }
    #pragma unroll
    for (int r = 0; r < RT; ++r) {
        Qb[(size_t)(row0 + r) * DIM + j] = f2bf(aq[r]);
        Kb[(size_t)(row0 + r) * DIM + j] = f2bf(ak[r]);
        Vb[(size_t)(row0 + r) * DIM + j] = f2bf(av[r]);
    }
}

// ---------------------------------------------------------------- CSR build
__global__ __launch_bounds__(256) void zero_deg_kernel(int* __restrict__ deg)
{
    const int i = blockIdx.x * 256 + threadIdx.x;
    if (i < NN) deg[i] = 0;
}

__global__ __launch_bounds__(256) void hist_kernel(
    const int* __restrict__ dst, int* __restrict__ deg)
{
    const int e = blockIdx.x * 256 + threadIdx.x;
    if (e < NE) atomicAdd(&deg[dst[e]], 1);
}

__global__ __launch_bounds__(1024) void scanA_kernel(
    const int* __restrict__ deg, int* __restrict__ rowptr,
    int* __restrict__ blocksum)
{
    __shared__ int s[1024];
    const int tid = threadIdx.x;
    const int i = blockIdx.x * 1024 + tid;
    const int v = (i < NN) ? deg[i] : 0;
    s[tid] = v;
    __syncthreads();
    for (int off = 1; off < 1024; off <<= 1) {
        const int add = (tid >= off) ? s[tid - off] : 0;
        __syncthreads();
        s[tid] += add;
        __syncthreads();
    }
    if (i < NN) rowptr[i] = s[tid] - v;        // exclusive, pre-offset
    if (tid == 1023) blocksum[blockIdx.x] = s[1023];
}

__global__ void scanB_kernel(const int* __restrict__ blocksum,
                             int* __restrict__ blockoff,
                             int* __restrict__ rowptr)
{
    if (blockIdx.x == 0 && threadIdx.x == 0) {
        int run = 0;
        for (int b = 0; b < NB; ++b) { blockoff[b] = run; run += blocksum[b]; }
        rowptr[NN] = run;    // == NE
    }
}

__global__ __launch_bounds__(256) void scanC_kernel(
    int* __restrict__ rowptr, int* __restrict__ cursor,
    const int* __restrict__ blockoff)
{
    const int i = blockIdx.x * 256 + threadIdx.x;
    if (i < NN) {
        const int r = rowptr[i] + blockoff[i >> 10];
        rowptr[i] = r;
        cursor[i] = r;
    }
}

// scatter edges into CSR order, materializing src, dst and the edge bias
// (edge_attr @ We) per CSR slot — removes the eid indirection downstream.
__global__ __launch_bounds__(256) void scatter_kernel(
    const int* __restrict__ dst, const int* __restrict__ src,
    const float* __restrict__ edge_attr, const float* __restrict__ We,
    int* __restrict__ cursor,
    int* __restrict__ srcp, int* __restrict__ dstp,
    float* __restrict__ eb_csr)
{
    const int e = blockIdx.x * 256 + threadIdx.x;
    if (e >= NE) return;
    const int d = dst[e];
    const int pos = atomicAdd(&cursor[d], 1);
    srcp[pos] = src[e];
    dstp[pos] = d;
    const float a0 = edge_attr[e * 3 + 0];
    const float a1 = edge_attr[e * 3 + 1];
    const float a2 = edge_attr[e * 3 + 2];
    float4 eb;
    eb.x = a0 * We[0] + a1 * We[4] + a2 * We[8];
    eb.y = a0 * We[1] + a1 * We[5] + a2 * We[9];
    eb.z = a0 * We[2] + a1 * We[6] + a2 * We[10];
    eb.w = a0 * We[3] + a1 * We[7] + a2 * We[11];
    *(float4*)(eb_csr + (size_t)pos * 4) = eb;
}

// ------------------------------------------------------- edge attention
// CSR-ordered: consecutive p share dst -> Q gather is cache-local; only
// K[src] is a true random gather. All other accesses sequential.
__global__ __launch_bounds__(256) void attn_kernel(
    const ushort* __restrict__ Qb, const ushort* __restrict__ Kb,
    const int* __restrict__ srcp, const int* __restrict__ dstp,
    const float* __restrict__ eb_csr,
    float* __restrict__ attn, float* __restrict__ blockmax)
{
    const int t = blockIdx.x * 256 + threadIdx.x;
    const int p = t >> 2;
    const int h = t & 3;
    const int s = srcp[p];
    const int d = dstp[p];
    const uint4* qv = (const uint4*)(Qb + (size_t)d * DIM + h * HD);
    const uint4* kv = (const uint4*)(Kb + (size_t)s * DIM + h * HD);
    float acc = 0.f;
    #pragma unroll
    for (int i = 0; i < 4; ++i) {
        const uint4 q = qv[i];
        const uint4 k = kv[i];
        acc += pairdot(q.x, k.x) + pairdot(q.y, k.y)
             + pairdot(q.z, k.z) + pairdot(q.w, k.w);
    }
    float a = acc * ATTN_SCALE + eb_csr[(size_t)p * 4 + h];
    a = (a >= 0.f) ? a : 0.2f * a;   // leaky_relu(0.2)
    attn[(size_t)p * 4 + h] = a;

    __shared__ float smax[256];
    smax[threadIdx.x] = a;
    __syncthreads();
    for (int s2 = 128; s2 > 0; s2 >>= 1) {
        if (threadIdx.x < s2)
            smax[threadIdx.x] = fmaxf(smax[threadIdx.x], smax[threadIdx.x + s2]);
        __syncthreads();
    }
    if (threadIdx.x == 0) blockmax[blockIdx.x] = smax[0];
}

__global__ __launch_bounds__(1024) void maxreduce_kernel(
    const float* __restrict__ blockmax, int n, float* __restrict__ gmax)
{
    __shared__ float smax[1024];
    float v = -INFINITY;
    for (int i = threadIdx.x; i < n; i += 1024) v = fmaxf(v, blockmax[i]);
    smax[threadIdx.x] = v;
    __syncthreads();
    for (int s = 512; s > 0; s >>= 1) {
        if (threadIdx.x < s)
            smax[threadIdx.x] = fmaxf(smax[threadIdx.x], smax[threadIdx.x + s]);
        __syncthreads();
    }
    if (threadIdx.x == 0) *gmax = smax[0];
}

// ------------------------------------------------------- CSR softmax+gather
// ONE WAVE PER NODE. Single pass: accumulate UNNORMALIZED sum(w*V) and
// sum(w) together (w = exp(attn - gmax) <= 1, no overflow), divide once at
// the end. 4-edge batches put 4 independent V-row loads in flight.
__global__ __launch_bounds__(256) void agg_gather_kernel(
    const float* __restrict__ attn, const float* __restrict__ gmax,
    const int* __restrict__ rowptr, const int* __restrict__ srcp,
    const ushort* __restrict__ Vb, float* __restrict__ aggout)
{
    const int tid = threadIdx.x;
    const int d = blockIdx.x * 4 + (tid >> 6);
    const int jj = tid & 63;          // column-pair index: cols 2jj, 2jj+1
    const int h = jj >> 4;            // head of both columns
    const float m = *gmax;
    const int begin = rowptr[d];
    const int end   = rowptr[d + 1];

    float ssum = 0.f;
    float a0 = 0.f, a1 = 0.f;
    int p = begin;
    for (; p + 4 <= end; p += 4) {
        const int s0 = srcp[p + 0];
        const int s1 = srcp[p + 1];
        const int s2 = srcp[p + 2];
        const int s3 = srcp[p + 3];
        const float w0 = __expf(attn[(size_t)(p + 0) * 4 + h] - m);
        const float w1 = __expf(attn[(size_t)(p + 1) * 4 + h] - m);
        const float w2 = __expf(attn[(size_t)(p + 2) * 4 + h] - m);
        const float w3 = __expf(attn[(size_t)(p + 3) * 4 + h] - m);
        const uint u0 = *(const uint*)(Vb + (size_t)s0 * DIM + 2 * jj);
        const uint u1 = *(const uint*)(Vb + (size_t)s1 * DIM + 2 * jj);
        const uint u2 = *(const uint*)(Vb + (size_t)s2 * DIM + 2 * jj);
        const uint u3 = *(const uint*)(Vb + (size_t)s3 * DIM + 2 * jj);
        ssum += (w0 + w1) + (w2 + w3);
        a0 = fmaf(bflo(u0), w0, a0); a1 = fmaf(bfhi(u0), w0, a1);
        a0 = fmaf(bflo(u1), w1, a0); a1 = fmaf(bfhi(u1), w1, a1);
        a0 = fmaf(bflo(u2), w2, a0); a1 = fmaf(bfhi(u2), w2, a1);
        a0 = fmaf(bflo(u3), w3, a0); a1 = fmaf(bfhi(u3), w3, a1);
    }
    for (; p < end; ++p) {
        const int s = srcp[p];
        const float w = __expf(attn[(size_t)p * 4 + h] - m);
        const uint u = *(const uint*)(Vb + (size_t)s * DIM + 2 * jj);
        ssum += w;
        a0 = fmaf(bflo(u), w, a0);
        a1 = fmaf(bfhi(u), w, a1);
    }
    const float inv = 1.f / fmaxf(ssum, 1e-12f);
    float2* outp = (float2*)(aggout + (size_t)d * DIM + 2 * jj);
    *outp = make_float2(a0 * inv, a1 * inv);
}

// ------------------------------------------------------- epilogue
// io == d_out: rows hold agg on entry, final output on exit (block-disjoint).
__global__ __launch_bounds__(128) void out_kernel(
    const float* __restrict__ x,
    const float* __restrict__ Wo, const float* __restrict__ bo,
    const float* __restrict__ Wm, const float* __restrict__ bm,
    float* __restrict__ io)
{
    __shared__ float xs[RT][DIM];
    __shared__ float as[RT][DIM];
    __shared__ float aggo[RT][DIM];
    const int j = threadIdx.x;
    const int row0 = blockIdx.x * RT;
    #pragma unroll
    for (int r = 0; r < RT; ++r) {
        xs[r][j] = x[(size_t)(row0 + r) * DIM + j];
        as[r][j] = io[(size_t)(row0 + r) * DIM + j];
    }
    __syncthreads();

    float acc[RT];
    {
        const float b = bo[j];
        #pragma unroll
        for (int r = 0; r < RT; ++r) acc[r] = b;
    }
    for (int k = 0; k < DIM; ++k) {
        const float wo = Wo[k * DIM + j];
        #pragma unroll
        for (int r = 0; r < RT; ++r) acc[r] = fmaf(as[r][k], wo, acc[r]);
    }
    #pragma unroll
    for (int r = 0; r < RT; ++r) aggo[r][j] = acc[r];
    __syncthreads();

    float acc2[RT];
    {
        const float b = bm[j];
        #pragma unroll
        for (int r = 0; r < RT; ++r) acc2[r] = b;
    }
    for (int k = 0; k < DIM; ++k) {
        const float wm = Wm[k * DIM + j];
        #pragma unroll
        for (int r = 0; r < RT; ++r) acc2[r] = fmaf(xs[r][k], wm, acc2[r]);
    }
    for (int k = 0; k < DIM; ++k) {
        const float wm = Wm[(DIM + k) * DIM + j];
        #pragma unroll
        for (int r = 0; r < RT; ++r) acc2[r] = fmaf(aggo[r][k], wm, acc2[r]);
    }
    #pragma unroll
    for (int r = 0; r < RT; ++r)
        io[(size_t)(row0 + r) * DIM + j] = fmaxf(acc2[r], 0.f);
}

// ----------------------------------------------------------------- launch
extern "C" void kernel_launch(void* const* d_in, const int* in_sizes, int n_in,
                              void* d_out, int out_size, void* d_ws, size_t ws_size,
                              hipStream_t stream)
{
    const float* x         = (const float*)d_in[0];
    const int*   edge_idx  = (const int*)d_in[1];   // [2,E]: row0=src, row1=dst
    const float* edge_attr = (const float*)d_in[2];
    const float* Wq        = (const float*)d_in[3];
    const float* Wk        = (const float*)d_in[4];
    const float* Wv        = (const float*)d_in[5];
    const float* We        = (const float*)d_in[6];
    const float* Wo        = (const float*)d_in[7];
    const float* bo        = (const float*)d_in[8];
    const float* Wm        = (const float*)d_in[9];
    const float* bm        = (const float*)d_in[10];
    float* out = (float*)d_out;

    const int* src = edge_idx;
    const int* dst = edge_idx + NE;

    // workspace layout (~71 MB)
    ushort* Qb = (ushort*)d_ws;                   // 6,400,000 us
    ushort* Kb = Qb + (size_t)NN * DIM;           // 6,400,000 us
    ushort* Vb = Kb + (size_t)NN * DIM;           // 6,400,000 us
    float* attn     = (float*)(Vb + (size_t)NN * DIM);  // 3,200,000 f (CSR order)
    float* eb_csr   = attn + (size_t)EH;          // 3,200,000 f
    float* blockmax = eb_csr + (size_t)EH;        // 12,544 f (12500 used)
    float* gmax     = blockmax + 12544;           // 64 f (1 used)
    int*   deg      = (int*)(gmax + 64);          // 50,048 i
    int*   rowptr   = deg + 50048;                // 50,048 i (50001 used)
    int*   cursor   = rowptr + 50048;             // 50,048 i
    int*   srcp     = cursor + 50048;             // 800,000 i
    int*   dstp     = srcp + 800000;              // 800,000 i
    int*   blocksum = dstp + 800000;              // 64 i (NB used)
    int*   blockoff = blocksum + 64;              // 64 i (NB used)

    const int attn_blocks = EH / 256;             // 12500 exact

    // CSR build (int atomics only)
    zero_deg_kernel<<<(NN + 255) / 256, 256, 0, stream>>>(deg);
    hist_kernel<<<(NE + 255) / 256, 256, 0, stream>>>(dst, deg);
    scanA_kernel<<<NB, 1024, 0, stream>>>(deg, rowptr, blocksum);
    scanB_kernel<<<1, 64, 0, stream>>>(blocksum, blockoff, rowptr);
    scanC_kernel<<<(NN + 255) / 256, 256, 0, stream>>>(rowptr, cursor, blockoff);
    scatter_kernel<<<(NE + 255) / 256, 256, 0, stream>>>(dst, src, edge_attr, We,
                                                         cursor, srcp, dstp, eb_csr);

    // main pipeline
    qkv_kernel<<<NN / RT, 128, 0, stream>>>(x, Wq, Wk, Wv, Qb, Kb, Vb);
    attn_kernel<<<attn_blocks, 256, 0, stream>>>(Qb, Kb, srcp, dstp, eb_csr,
                                                 attn, blockmax);
    maxreduce_kernel<<<1, 1024, 0, stream>>>(blockmax, attn_blocks, gmax);
    agg_gather_kernel<<<NN / 4, 256, 0, stream>>>(attn, gmax, rowptr, srcp,
                                                  Vb, out);
    out_kernel<<<NN / RT, 128, 0, stream>>>(x, Wo, bo, Wm, bm, out);
}

// Round 6
// 327.908 us; speedup vs baseline: 3.7717x; 1.4525x over previous
//
#include <hip/hip_runtime.h>
#include <hip/hip_bf16.h>
#include <math.h>

#define NN 50000
#define NE 800000
#define DIM 128
#define NH 4
#define HD 32
#define EH (NE * NH)          // 3,200,000
#define ATTN_SCALE 0.17677669529663687f   // 1/sqrt(32)
#define NB 49                 // scan blocks: ceil(50000/1024)
#define MTILE 64
#define GEMM_BLOCKS 782       // ceil(50000/64)

typedef unsigned int uint;
typedef unsigned short ushort;
typedef __attribute__((ext_vector_type(8))) short short8;   // 8 bf16 (4 VGPRs)
typedef __attribute__((ext_vector_type(4))) float f32x4;    // MFMA acc

__device__ inline ushort f2bf(float f) {
    __hip_bfloat16 h = __float2bfloat16(f);   // round-to-nearest
    return *(ushort*)&h;
}
__device__ inline float bflo(uint u) { return __uint_as_float(u << 16); }
__device__ inline float bfhi(uint u) { return __uint_as_float(u & 0xffff0000u); }
__device__ inline float pairdot(uint q, uint k) {
    return fmaf(bflo(q), bflo(k), bfhi(q) * bfhi(k));
}

// ---------------------------------------------------------------- prep
// x fp32 -> xb bf16 (row-major), float4 loads.
__global__ __launch_bounds__(256) void prep_x_kernel(
    const float* __restrict__ x, ushort* __restrict__ xb)
{
    const int i = blockIdx.x * 256 + threadIdx.x;     // one per 4 elems
    const float4 v = ((const float4*)x)[i];
    ushort4 o;
    o.x = f2bf(v.x); o.y = f2bf(v.y); o.z = f2bf(v.z); o.w = f2bf(v.w);
    ((ushort4*)xb)[i] = o;
}

// Wx = Wo @ Wm2  (Wm2 = rows 128..255 of Wm), fp32. grid 128 (r), block 128 (j).
__global__ __launch_bounds__(128) void prep_wx_kernel(
    const float* __restrict__ Wo, const float* __restrict__ Wm,
    float* __restrict__ Wx)
{
    const int r = blockIdx.x, j = threadIdx.x;
    float acc = 0.f;
    for (int t = 0; t < 128; ++t)
        acc = fmaf(Wo[r * 128 + t], Wm[(128 + t) * 128 + j], acc);
    Wx[r * 128 + j] = acc;
}

// b' = bo @ Wm2 + bm. one block of 128.
__global__ __launch_bounds__(128) void prep_bias_kernel(
    const float* __restrict__ bo, const float* __restrict__ bm,
    const float* __restrict__ Wm, float* __restrict__ bprime)
{
    const int j = threadIdx.x;
    float acc = bm[j];
    for (int t = 0; t < 128; ++t)
        acc = fmaf(bo[t], Wm[(128 + t) * 128 + j], acc);
    bprime[j] = acc;
}

// Pack B operands into MFMA fragment order:
// flat = ((kc*NT + nt)*64 + lane)*8 + j  holds  B[kc*32 + (lane>>4)*8 + j][nt*16 + (lane&15)]
__global__ __launch_bounds__(256) void pack_qkv_kernel(
    const float* __restrict__ Wq, const float* __restrict__ Wk,
    const float* __restrict__ Wv, short* __restrict__ Bp)
{
    const int idx = blockIdx.x * 256 + threadIdx.x;   // 4*24*64*8 = 49152
    const int j = idx & 7, lane = (idx >> 3) & 63;
    const int rest = idx >> 9;                        // kc*24 + nt
    const int nt = rest % 24, kc = rest / 24;
    const int k = kc * 32 + (lane >> 4) * 8 + j;
    const int n = nt * 16 + (lane & 15);
    const float* W = (n < 128) ? Wq : (n < 256 ? Wk : Wv);
    Bp[idx] = (short)f2bf(W[k * 128 + (n & 127)]);
}

__global__ __launch_bounds__(256) void pack_out_kernel(
    const float* __restrict__ Wm, const float* __restrict__ Wx,
    short* __restrict__ Bp)
{
    const int idx = blockIdx.x * 256 + threadIdx.x;   // 8*8*64*8 = 32768
    const int j = idx & 7, lane = (idx >> 3) & 63;
    const int rest = idx >> 9;                        // kc*8 + nt
    const int nt = rest & 7, kc = rest >> 3;
    const int k = kc * 32 + (lane >> 4) * 8 + j;
    const int n = nt * 16 + (lane & 15);
    const float v = (k < 128) ? Wm[k * 128 + n] : Wx[(k - 128) * 128 + n];
    Bp[idx] = (short)f2bf(v);
}

// ---------------------------------------------------------------- CSR build
__global__ __launch_bounds__(256) void zero_deg_kernel(int* __restrict__ deg)
{
    const int i = blockIdx.x * 256 + threadIdx.x;
    if (i < NN) deg[i] = 0;
}

__global__ __launch_bounds__(256) void hist_kernel(
    const int* __restrict__ dst, int* __restrict__ deg)
{
    const int e = blockIdx.x * 256 + threadIdx.x;
    if (e < NE) atomicAdd(&deg[dst[e]], 1);
}

__global__ __launch_bounds__(1024) void scanA_kernel(
    const int* __restrict__ deg, int* __restrict__ rowptr,
    int* __restrict__ blocksum)
{
    __shared__ int s[1024];
    const int tid = threadIdx.x;
    const int i = blockIdx.x * 1024 + tid;
    const int v = (i < NN) ? deg[i] : 0;
    s[tid] = v;
    __syncthreads();
    for (int off = 1; off < 1024; off <<= 1) {
        const int add = (tid >= off) ? s[tid - off] : 0;
        __syncthreads();
        s[tid] += add;
        __syncthreads();
    }
    if (i < NN) rowptr[i] = s[tid] - v;
    if (tid == 1023) blocksum[blockIdx.x] = s[1023];
}

__global__ void scanB_kernel(const int* __restrict__ blocksum,
                             int* __restrict__ blockoff,
                             int* __restrict__ rowptr)
{
    if (blockIdx.x == 0 && threadIdx.x == 0) {
        int run = 0;
        for (int b = 0; b < NB; ++b) { blockoff[b] = run; run += blocksum[b]; }
        rowptr[NN] = run;    // == NE
    }
}

__global__ __launch_bounds__(256) void scanC_kernel(
    int* __restrict__ rowptr, int* __restrict__ cursor,
    const int* __restrict__ blockoff)
{
    const int i = blockIdx.x * 256 + threadIdx.x;
    if (i < NN) {
        const int r = rowptr[i] + blockoff[i >> 10];
        rowptr[i] = r;
        cursor[i] = r;
    }
}

__global__ __launch_bounds__(256) void scatter_kernel(
    const int* __restrict__ dst, const int* __restrict__ src,
    const float* __restrict__ edge_attr, const float* __restrict__ We,
    int* __restrict__ cursor,
    int* __restrict__ srcp, int* __restrict__ dstp,
    float* __restrict__ eb_csr)
{
    const int e = blockIdx.x * 256 + threadIdx.x;
    if (e >= NE) return;
    const int d = dst[e];
    const int pos = atomicAdd(&cursor[d], 1);
    srcp[pos] = src[e];
    dstp[pos] = d;
    const float a0 = edge_attr[e * 3 + 0];
    const float a1 = edge_attr[e * 3 + 1];
    const float a2 = edge_attr[e * 3 + 2];
    float4 eb;
    eb.x = a0 * We[0] + a1 * We[4] + a2 * We[8];
    eb.y = a0 * We[1] + a1 * We[5] + a2 * We[9];
    eb.z = a0 * We[2] + a1 * We[6] + a2 * We[10];
    eb.w = a0 * We[3] + a1 * We[7] + a2 * We[11];
    *(float4*)(eb_csr + (size_t)pos * 4) = eb;
}

// ---------------------------------------------------------------- QKV MFMA
// xb[50000x128] @ Bp(packed [Wq|Wk|Wv], 128x384) -> Qb,Kb,Vb bf16.
// Per block: 4 waves x 16 rows = 64-row tile. No LDS.
__global__ __launch_bounds__(256) void qkv_mfma_kernel(
    const ushort* __restrict__ xb, const short* __restrict__ Bp,
    ushort* __restrict__ Qb, ushort* __restrict__ Kb, ushort* __restrict__ Vb)
{
    const int wave = threadIdx.x >> 6;
    const int lane = threadIdx.x & 63;
    const int m = lane & 15, quad = lane >> 4;
    const int row0w = blockIdx.x * MTILE + wave * 16;
    const int arow = row0w + m;
    const bool rowok = arow < NN;

    short8 a[4];
    #pragma unroll
    for (int kc = 0; kc < 4; ++kc)
        a[kc] = rowok ? *(const short8*)(xb + (size_t)arow * 128 + kc * 32 + quad * 8)
                      : (short8)(0);

    const int NT = 24;
    for (int nt = 0; nt < NT; nt += 2) {
        f32x4 acc0 = {0.f, 0.f, 0.f, 0.f}, acc1 = {0.f, 0.f, 0.f, 0.f};
        #pragma unroll
        for (int kc = 0; kc < 4; ++kc) {
            const short8 b0 = *(const short8*)(Bp + ((size_t)(kc * NT + nt) * 64 + lane) * 8);
            const short8 b1 = *(const short8*)(Bp + ((size_t)(kc * NT + nt + 1) * 64 + lane) * 8);
            acc0 = __builtin_amdgcn_mfma_f32_16x16x32_bf16(a[kc], b0, acc0, 0, 0, 0);
            acc1 = __builtin_amdgcn_mfma_f32_16x16x32_bf16(a[kc], b1, acc1, 0, 0, 0);
        }
        #pragma unroll
        for (int t = 0; t < 2; ++t) {
            const f32x4 acc = t ? acc1 : acc0;
            const int c = (nt + t) * 16 + m;           // global col in [0,384)
            ushort* dst = (c < 128) ? Qb : (c < 256 ? Kb : Vb);
            const int lc = c & 127;
            #pragma unroll
            for (int g = 0; g < 4; ++g) {
                const int r = row0w + quad * 4 + g;
                if (r < NN) dst[(size_t)r * 128 + lc] = f2bf(acc[g]);
            }
        }
    }
}

// ---------------------------------------------------------------- OUT MFMA
// [xb|aggb][50000x256] @ Bp(packed [Wm1;Wx], 256x128) + b' -> relu -> d_out.
__global__ __launch_bounds__(256) void out_mfma_kernel(
    const ushort* __restrict__ xb, const ushort* __restrict__ aggb,
    const short* __restrict__ Bp, const float* __restrict__ bprime,
    float* __restrict__ out)
{
    const int wave = threadIdx.x >> 6;
    const int lane = threadIdx.x & 63;
    const int m = lane & 15, quad = lane >> 4;
    const int row0w = blockIdx.x * MTILE + wave * 16;
    const int arow = row0w + m;
    const bool rowok = arow < NN;

    short8 a[8];
    #pragma unroll
    for (int kc = 0; kc < 4; ++kc)
        a[kc] = rowok ? *(const short8*)(xb + (size_t)arow * 128 + kc * 32 + quad * 8)
                      : (short8)(0);
    #pragma unroll
    for (int kc = 0; kc < 4; ++kc)
        a[4 + kc] = rowok ? *(const short8*)(aggb + (size_t)arow * 128 + kc * 32 + quad * 8)
                          : (short8)(0);

    const int NT = 8;
    for (int nt = 0; nt < NT; nt += 2) {
        f32x4 acc0 = {0.f, 0.f, 0.f, 0.f}, acc1 = {0.f, 0.f, 0.f, 0.f};
        #pragma unroll
        for (int kc = 0; kc < 8; ++kc) {
            const short8 b0 = *(const short8*)(Bp + ((size_t)(kc * NT + nt) * 64 + lane) * 8);
            const short8 b1 = *(const short8*)(Bp + ((size_t)(kc * NT + nt + 1) * 64 + lane) * 8);
            acc0 = __builtin_amdgcn_mfma_f32_16x16x32_bf16(a[kc], b0, acc0, 0, 0, 0);
            acc1 = __builtin_amdgcn_mfma_f32_16x16x32_bf16(a[kc], b1, acc1, 0, 0, 0);
        }
        #pragma unroll
        for (int t = 0; t < 2; ++t) {
            const f32x4 acc = t ? acc1 : acc0;
            const int c = (nt + t) * 16 + m;           // global col in [0,128)
            const float bb = bprime[c];
            #pragma unroll
            for (int g = 0; g < 4; ++g) {
                const int r = row0w + quad * 4 + g;
                if (r < NN) out[(size_t)r * 128 + c] = fmaxf(acc[g] + bb, 0.f);
            }
        }
    }
}

// ------------------------------------------------------- edge attention
__global__ __launch_bounds__(256) void attn_kernel(
    const ushort* __restrict__ Qb, const ushort* __restrict__ Kb,
    const int* __restrict__ srcp, const int* __restrict__ dstp,
    const float* __restrict__ eb_csr,
    float* __restrict__ attn, float* __restrict__ blockmax)
{
    const int t = blockIdx.x * 256 + threadIdx.x;
    const int p = t >> 2;
    const int h = t & 3;
    const int s = srcp[p];
    const int d = dstp[p];
    const uint4* qv = (const uint4*)(Qb + (size_t)d * DIM + h * HD);
    const uint4* kv = (const uint4*)(Kb + (size_t)s * DIM + h * HD);
    float acc = 0.f;
    #pragma unroll
    for (int i = 0; i < 4; ++i) {
        const uint4 q = qv[i];
        const uint4 k = kv[i];
        acc += pairdot(q.x, k.x) + pairdot(q.y, k.y)
             + pairdot(q.z, k.z) + pairdot(q.w, k.w);
    }
    float a = acc * ATTN_SCALE + eb_csr[(size_t)p * 4 + h];
    a = (a >= 0.f) ? a : 0.2f * a;   // leaky_relu(0.2)
    attn[(size_t)p * 4 + h] = a;

    __shared__ float smax[256];
    smax[threadIdx.x] = a;
    __syncthreads();
    for (int s2 = 128; s2 > 0; s2 >>= 1) {
        if (threadIdx.x < s2)
            smax[threadIdx.x] = fmaxf(smax[threadIdx.x], smax[threadIdx.x + s2]);
        __syncthreads();
    }
    if (threadIdx.x == 0) blockmax[blockIdx.x] = smax[0];
}

__global__ __launch_bounds__(1024) void maxreduce_kernel(
    const float* __restrict__ blockmax, int n, float* __restrict__ gmax)
{
    __shared__ float smax[1024];
    float v = -INFINITY;
    for (int i = threadIdx.x; i < n; i += 1024) v = fmaxf(v, blockmax[i]);
    smax[threadIdx.x] = v;
    __syncthreads();
    for (int s = 512; s > 0; s >>= 1) {
        if (threadIdx.x < s)
            smax[threadIdx.x] = fmaxf(smax[threadIdx.x], smax[threadIdx.x + s]);
        __syncthreads();
    }
    if (threadIdx.x == 0) *gmax = smax[0];
}

// ------------------------------------------------------- CSR softmax+gather
// One wave per node; single pass (unnormalized acc + weight sum); bf16 out.
__global__ __launch_bounds__(256) void agg_gather_kernel(
    const float* __restrict__ attn, const float* __restrict__ gmax,
    const int* __restrict__ rowptr, const int* __restrict__ srcp,
    const ushort* __restrict__ Vb, ushort* __restrict__ aggb)
{
    const int tid = threadIdx.x;
    const int d = blockIdx.x * 4 + (tid >> 6);
    const int jj = tid & 63;          // column-pair index: cols 2jj, 2jj+1
    const int h = jj >> 4;            // head of both columns
    const float m = *gmax;
    const int begin = rowptr[d];
    const int end   = rowptr[d + 1];

    float ssum = 0.f;
    float a0 = 0.f, a1 = 0.f;
    int p = begin;
    for (; p + 4 <= end; p += 4) {
        const int s0 = srcp[p + 0];
        const int s1 = srcp[p + 1];
        const int s2 = srcp[p + 2];
        const int s3 = srcp[p + 3];
        const float w0 = __expf(attn[(size_t)(p + 0) * 4 + h] - m);
        const float w1 = __expf(attn[(size_t)(p + 1) * 4 + h] - m);
        const float w2 = __expf(attn[(size_t)(p + 2) * 4 + h] - m);
        const float w3 = __expf(attn[(size_t)(p + 3) * 4 + h] - m);
        const uint u0 = *(const uint*)(Vb + (size_t)s0 * DIM + 2 * jj);
        const uint u1 = *(const uint*)(Vb + (size_t)s1 * DIM + 2 * jj);
        const uint u2 = *(const uint*)(Vb + (size_t)s2 * DIM + 2 * jj);
        const uint u3 = *(const uint*)(Vb + (size_t)s3 * DIM + 2 * jj);
        ssum += (w0 + w1) + (w2 + w3);
        a0 = fmaf(bflo(u0), w0, a0); a1 = fmaf(bfhi(u0), w0, a1);
        a0 = fmaf(bflo(u1), w1, a0); a1 = fmaf(bfhi(u1), w1, a1);
        a0 = fmaf(bflo(u2), w2, a0); a1 = fmaf(bfhi(u2), w2, a1);
        a0 = fmaf(bflo(u3), w3, a0); a1 = fmaf(bfhi(u3), w3, a1);
    }
    for (; p < end; ++p) {
        const int s = srcp[p];
        const float w = __expf(attn[(size_t)p * 4 + h] - m);
        const uint u = *(const uint*)(Vb + (size_t)s * DIM + 2 * jj);
        ssum += w;
        a0 = fmaf(bflo(u), w, a0);
        a1 = fmaf(bfhi(u), w, a1);
    }
    const float inv = 1.f / fmaxf(ssum, 1e-12f);
    const uint packed = (uint)f2bf(a0 * inv) | ((uint)f2bf(a1 * inv) << 16);
    *(uint*)(aggb + (size_t)d * DIM + 2 * jj) = packed;
}

// ----------------------------------------------------------------- launch
extern "C" void kernel_launch(void* const* d_in, const int* in_sizes, int n_in,
                              void* d_out, int out_size, void* d_ws, size_t ws_size,
                              hipStream_t stream)
{
    const float* x         = (const float*)d_in[0];
    const int*   edge_idx  = (const int*)d_in[1];   // [2,E]: row0=src, row1=dst
    const float* edge_attr = (const float*)d_in[2];
    const float* Wq        = (const float*)d_in[3];
    const float* Wk        = (const float*)d_in[4];
    const float* Wv        = (const float*)d_in[5];
    const float* We        = (const float*)d_in[6];
    const float* Wo        = (const float*)d_in[7];
    const float* bo        = (const float*)d_in[8];
    const float* Wm        = (const float*)d_in[9];
    const float* bm        = (const float*)d_in[10];
    float* out = (float*)d_out;

    const int* src = edge_idx;
    const int* dst = edge_idx + NE;

    // workspace layout (all sections 16B-aligned)
    ushort* xb   = (ushort*)d_ws;                 // 6,400,000 us
    ushort* Qb   = xb + (size_t)NN * DIM;         // 6,400,000 us
    ushort* Kb   = Qb + (size_t)NN * DIM;         // 6,400,000 us
    ushort* Vb   = Kb + (size_t)NN * DIM;         // 6,400,000 us
    ushort* aggb = Vb + (size_t)NN * DIM;         // 6,400,000 us
    float* attn     = (float*)(aggb + (size_t)NN * DIM);  // 3,200,000 f
    float* eb_csr   = attn + (size_t)EH;          // 3,200,000 f
    float* blockmax = eb_csr + (size_t)EH;        // 12,544 f
    float* gmax     = blockmax + 12544;           // 64 f
    float* Wx       = gmax + 64;                  // 16,384 f
    float* bprime   = Wx + 16384;                 // 128 f
    short* BpQKV    = (short*)(bprime + 128);     // 49,152 s
    short* BpOut    = BpQKV + 49152;              // 32,768 s
    int*   deg      = (int*)(BpOut + 32768);      // 50,048 i
    int*   rowptr   = deg + 50048;                // 50,048 i (50001 used)
    int*   cursor   = rowptr + 50048;             // 50,048 i
    int*   srcp     = cursor + 50048;             // 800,000 i
    int*   dstp     = srcp + 800000;              // 800,000 i
    int*   blocksum = dstp + 800000;              // 64 i
    int*   blockoff = blocksum + 64;              // 64 i

    const int attn_blocks = EH / 256;             // 12500 exact

    // prep: bf16 x, fused epilogue weights, packed B operands
    prep_x_kernel<<<(NN * DIM / 4) / 256, 256, 0, stream>>>(x, xb);
    prep_wx_kernel<<<128, 128, 0, stream>>>(Wo, Wm, Wx);
    prep_bias_kernel<<<1, 128, 0, stream>>>(bo, bm, Wm, bprime);
    pack_qkv_kernel<<<192, 256, 0, stream>>>(Wq, Wk, Wv, BpQKV);
    pack_out_kernel<<<128, 256, 0, stream>>>(Wm, Wx, BpOut);

    // CSR build
    zero_deg_kernel<<<(NN + 255) / 256, 256, 0, stream>>>(deg);
    hist_kernel<<<(NE + 255) / 256, 256, 0, stream>>>(dst, deg);
    scanA_kernel<<<NB, 1024, 0, stream>>>(deg, rowptr, blocksum);
    scanB_kernel<<<1, 64, 0, stream>>>(blocksum, blockoff, rowptr);
    scanC_kernel<<<(NN + 255) / 256, 256, 0, stream>>>(rowptr, cursor, blockoff);
    scatter_kernel<<<(NE + 255) / 256, 256, 0, stream>>>(dst, src, edge_attr, We,
                                                         cursor, srcp, dstp, eb_csr);

    // main pipeline
    qkv_mfma_kernel<<<GEMM_BLOCKS, 256, 0, stream>>>(xb, BpQKV, Qb, Kb, Vb);
    attn_kernel<<<attn_blocks, 256, 0, stream>>>(Qb, Kb, srcp, dstp, eb_csr,
                                                 attn, blockmax);
    maxreduce_kernel<<<1, 1024, 0, stream>>>(blockmax, attn_blocks, gmax);
    agg_gather_kernel<<<NN / 4, 256, 0, stream>>>(attn, gmax, rowptr, srcp,
                                                  Vb, aggb);
    out_mfma_kernel<<<GEMM_BLOCKS, 256, 0, stream>>>(xb, aggb, BpOut, bprime, out);
}